// Round 11
// baseline (485.896 us; speedup 1.0000x reference)
//
#include <hip/hip_runtime.h>
#include <hip/hip_bf16.h>

// DNRI step: B=32, N=100, D=4, H=256, K=4 (skip type 0), E=9900.
// R10: R9 + runtime p-loop (#pragma unroll 1). R9's unrolled two-pass GEMM
// kept BOTH acc[7][2] sets live (112 AGPR) -> 172 arch + 112 = 284 > 256
// -> 1 wave/SIMD (occupancy 11.4%, matches all prior rounds' accounting).
// Serializing the passes keeps one acc set (56) -> ~228 total -> 2 waves/SIMD.
// Runtime-p hazards (rule #20) removed: b2 loaded inside the loop, aggacc
// updated via uniform if(p==0) with static indices.

typedef __attribute__((ext_vector_type(4))) float f32x4;
typedef __attribute__((ext_vector_type(8))) short s16x8;
typedef __attribute__((ext_vector_type(4))) unsigned short u16x4;
typedef __attribute__((ext_vector_type(4))) unsigned int u32x4;
typedef __attribute__((ext_vector_type(2))) unsigned int u32x2;

#define DEV static __device__ __forceinline__

DEV unsigned short f2bf(float f) {
  unsigned int u = __builtin_bit_cast(unsigned int, f);
  u += 0x7fffu + ((u >> 16) & 1u);   // RNE
  return (unsigned short)(u >> 16);
}
DEV float bf2f(unsigned short h) {
  unsigned int u = ((unsigned int)h) << 16;
  return __builtin_bit_cast(float, u);
}
DEV float bflo(unsigned int u) { return __builtin_bit_cast(float, u << 16); }
DEV float bfhi(unsigned int u) { return __builtin_bit_cast(float, u & 0xffff0000u); }
DEV float exp2_fast(float x) { return __builtin_amdgcn_exp2f(x); }
DEV float tanh_fast(float x) {
  float e = exp2_fast(x * 2.885390082f);            // exp(2x)
  return 1.f - 2.f * __builtin_amdgcn_rcpf(e + 1.f);
}
DEV float sigmoid_fast(float x) {
  return __builtin_amdgcn_rcpf(1.f + exp2_fast(-1.442695041f * x));
}
DEV unsigned int pk_fp8x4(float a, float b, float c, float d) {
  int v = __builtin_amdgcn_cvt_pk_fp8_f32(a, b, 0, false);   // bytes 0,1
  v = __builtin_amdgcn_cvt_pk_fp8_f32(c, d, v, true);        // bytes 2,3
  return (unsigned int)v;
}

// ---- LDS staging: 64 rows x 256 bf16, XOR-swizzled ----
DEV void stage_bf16_64(const unsigned short* __restrict__ src, unsigned char* smem, int tid) {
#pragma unroll
  for (int j = 0; j < 8; ++j) {
    int c = tid + 256 * j;
    int s = c >> 5, hc = c & 31;
    s16x8 v = *reinterpret_cast<const s16x8*>(src + s * 256 + hc * 8);
    int byte = (s * 512 + hc * 16) ^ ((s & 7) << 4);
    *reinterpret_cast<s16x8*>(smem + byte) = v;
  }
}
DEV void stage_f32_64(const float* __restrict__ src, unsigned char* smem, int tid) {
#pragma unroll
  for (int j = 0; j < 8; ++j) {
    int c = tid + 256 * j;
    int s = c >> 5, hc = c & 31;
    const float* p = src + s * 256 + hc * 8;
    f32x4 v0 = *reinterpret_cast<const f32x4*>(p);
    f32x4 v1 = *reinterpret_cast<const f32x4*>(p + 4);
    s16x8 o;
#pragma unroll
    for (int i = 0; i < 4; ++i) { o[i] = (short)f2bf(v0[i]); o[4 + i] = (short)f2bf(v1[i]); }
    int byte = (s * 512 + hc * 16) ^ ((s & 7) << 4);
    *reinterpret_cast<s16x8*>(smem + byte) = o;
  }
}

// ---- bf16 MFMA tile helper (A in swizzled LDS, B^T [n][k] bf16 in global) ----
template<int MF>
DEV void gemm_lds_tile(const unsigned char* smemA, const unsigned short* __restrict__ B,
                       int nb, int lane, f32x4 acc[][4]) {
  int li = lane & 15, lg = lane >> 4;
#pragma unroll
  for (int kk = 0; kk < 8; ++kk) {
    int kb = kk * 32 + lg * 8;
    s16x8 a[MF];
#pragma unroll
    for (int m = 0; m < MF; ++m) {
      int row = m * 16 + li;
      int byte = (row * 512 + kb * 2) ^ ((row & 7) << 4);
      a[m] = *reinterpret_cast<const s16x8*>(smemA + byte);
    }
#pragma unroll
    for (int n = 0; n < 4; ++n) {
      int col = nb + n * 16 + li;
      s16x8 bf = *reinterpret_cast<const s16x8*>(B + col * 256 + kb);
#pragma unroll
      for (int m = 0; m < MF; ++m)
        acc[m][n] = __builtin_amdgcn_mfma_f32_16x16x32_bf16(a[m], bf, acc[m][n], 0, 0, 0);
    }
  }
}

// ---- K0: bf16 transposes (W1a/W1b/Wh-family) ----
__global__ __launch_bounds__(256) void k0_pack(
    const float* __restrict__ msg_W1,
    const float* __restrict__ Whr, const float* __restrict__ Whi, const float* __restrict__ Whh,
    const float* __restrict__ Wo1, const float* __restrict__ Wo2,
    unsigned short* __restrict__ W1aT, unsigned short* __restrict__ W1bT,
    unsigned short* __restrict__ WhT) {
  int g = blockIdx.x * 256 + threadIdx.x;
  if (g < 196608) {               // W1aT[ti][n][k] = msg_W1[ti+1][k][n]
    int ti = g >> 16, rem = g & 65535, n = rem >> 8, k = rem & 255;
    W1aT[g] = f2bf(msg_W1[((ti + 1) * 512 + k) * 256 + n]);
  } else if (g < 393216) {        // W1bT[ti][n][k] = msg_W1[ti+1][256+k][n]
    int h = g - 196608; int ti = h >> 16, rem = h & 65535, n = rem >> 8, k = rem & 255;
    W1bT[h] = f2bf(msg_W1[((ti + 1) * 512 + 256 + k) * 256 + n]);
  } else if (g < 720896) {        // WhT: {Whr,Whi,Whh,Wo1,Wo2}^T
    int h = g - 393216; int mi = h >> 16, rem = h & 65535, n = rem >> 8, k = rem & 255;
    const float* s = mi == 0 ? Whr : mi == 1 ? Whi : mi == 2 ? Whh : mi == 3 ? Wo1 : Wo2;
    WhT[h] = f2bf(s[k * 256 + n]);
  }
}

// ---- K0q: W2 -> fp8 e4m3, layout [ti][col][k] (1B/elem) ----
__global__ __launch_bounds__(256) void k0_quant(
    const float* __restrict__ msg_W2, unsigned short* __restrict__ W2Q) {
  int g = blockIdx.x * 256 + threadIdx.x;          // 98304 = 3*256*128
  int ti = g >> 15, rem = g & 32767, col = rem >> 7, k2 = rem & 127;
  int k = k2 * 2;
  const float* src = msg_W2 + (size_t)(ti + 1) * 65536;
  float a = src[k * 256 + col], b = src[(k + 1) * 256 + col];
  int v = __builtin_amdgcn_cvt_pk_fp8_f32(a, b, 0, false);
  W2Q[g] = (unsigned short)(v & 0xffff);
}

// ---- Xpre[row][3*256] = inputs @ [Wir|Wii|Win] + biases ----
__global__ __launch_bounds__(256) void k_xpre(
    const float* __restrict__ inputs, const float* __restrict__ Wir, const float* __restrict__ bir,
    const float* __restrict__ Wii, const float* __restrict__ bii,
    const float* __restrict__ Win, const float* __restrict__ bin_, float* __restrict__ Xpre) {
  int g = blockIdx.x * 256 + threadIdx.x;   // 3200*768 exact
  int row = g / 768, c = g % 768, which = c >> 8, col = c & 255;
  const float* W = which == 0 ? Wir : which == 1 ? Wii : Win;
  const float* bb = which == 0 ? bir : which == 1 ? bii : bin_;
  const float* inp = inputs + row * 4;
  float s = bb[col];
#pragma unroll
  for (int d = 0; d < 4; ++d) s += inp[d] * W[d * 256 + col];
  Xpre[g] = s;
}

// ---- K1: Ha[ti] = hidden@W1a+b1 (bf16), Hb[ti] = hidden@W1b ----
__global__ __launch_bounds__(256) void k1_nodepre(
    const float* __restrict__ hidden, const float* __restrict__ msg_b1,
    const unsigned short* __restrict__ W1aT, const unsigned short* __restrict__ W1bT,
    unsigned short* __restrict__ Ha, unsigned short* __restrict__ Hb) {
  __shared__ alignas(16) unsigned char smem[32768];
  int tid = threadIdx.x, lane = tid & 63, wv = tid >> 6;
  int mt = blockIdx.x, g = blockIdx.y;
  stage_f32_64(hidden + (size_t)mt * 64 * 256, smem, tid);
  __syncthreads();
  int ti = g < 3 ? g : g - 3;
  const unsigned short* Bp = (g < 3 ? W1aT : W1bT) + ti * 65536;
  f32x4 zz = {0.f, 0.f, 0.f, 0.f};
  f32x4 acc[4][4];
#pragma unroll
  for (int m = 0; m < 4; ++m)
#pragma unroll
    for (int n = 0; n < 4; ++n) acc[m][n] = zz;
  gemm_lds_tile<4>(smem, Bp, wv * 64, lane, acc);
  unsigned short* dst = (g < 3 ? Ha : Hb) + (size_t)ti * 819200 + (size_t)mt * 64 * 256;
  int li = lane & 15, lg = lane >> 4;
#pragma unroll
  for (int n = 0; n < 4; ++n) {
    int col = wv * 64 + n * 16 + li;
    float bias = g < 3 ? msg_b1[(ti + 1) * 256 + col] : 0.f;
#pragma unroll
    for (int m = 0; m < 4; ++m)
#pragma unroll
      for (int q = 0; q < 4; ++q) {
        int row = m * 16 + lg * 4 + q;
        dst[row * 256 + col] = f2bf(acc[m][n][q] + bias);
      }
  }
}

// ---- K2: per-(b, receiver) edge messages + weighted aggregation (hot kernel) ----
// 256 threads = 4 waves, each owning 64 output cols (two SERIAL 32-col passes).
// LDS: m1 fp8 [112][256B] swizzled @0 (28672) | w [3][112] f32 @28672 | agg [256] f32 @30016
__global__ __launch_bounds__(256) void k2_edges(
    const float* __restrict__ edges, const float* __restrict__ msg_b2,
    const unsigned short* __restrict__ Ha, const unsigned short* __restrict__ Hb,
    const unsigned char* __restrict__ W2Q, unsigned short* __restrict__ aggbf) {
  __shared__ alignas(16) unsigned char smem[31040];
  float* w_s = (float*)(smem + 28672);
  float* agg_s = (float*)(smem + 30016);
  int tid = threadIdx.x, lane = tid & 63, wv = tid >> 6;
  int li = lane & 15, lg = lane >> 4;
  // XCD-contiguous swizzle (bijective: 3200 = 8*400)
  int bid0 = blockIdx.x;
  int bid = (bid0 & 7) * 400 + (bid0 >> 3);
  int b = bid / 100, r = bid % 100;

  // phase 0: edge weights (analytic dense edge index)
  if (tid < 112) {
    float w0 = 0.f, w1 = 0.f, w2 = 0.f;
    if (tid < 99) {
      int snode = tid + (tid >= r ? 1 : 0);
      int e = snode * 99 + r - (r > snode ? 1 : 0);
      f32x4 ew = *reinterpret_cast<const f32x4*>(edges + (size_t)(b * 9900 + e) * 4);
      const float inv = 1.f / 297.f;   // /norm(3) /(N-1)(99)
      w0 = ew[1] * inv; w1 = ew[2] * inv; w2 = ew[3] * inv;
    }
    w_s[tid] = w0; w_s[112 + tid] = w1; w_s[224 + tid] = w2;
  }

  int hc = tid & 31;        // fixed 8-col group in the build
  int srow0 = tid >> 5;     // build row within each 8-row stripe
  float agg0 = 0.f, agg1 = 0.f, agg2 = 0.f, agg3 = 0.f;
  f32x4 zz = {0.f, 0.f, 0.f, 0.f};

  for (int ti = 0; ti < 3; ++ti) {
    // prefetch receiver row for this type
    u32x4 hau = *reinterpret_cast<const u32x4*>(
        Ha + ((size_t)ti * 3200 + b * 100 + r) * 256 + hc * 8);

    __syncthreads();   // prev GEMM done reading m1 (w_s ready at ti==0)

    // build m1[s][h] = fp8(tanh(Ha[r][h] + Hb[snode][h])); rows 99..111 zero
    float ha_f[8];
#pragma unroll
    for (int i = 0; i < 4; ++i) { ha_f[2 * i] = bflo(hau[i]); ha_f[2 * i + 1] = bfhi(hau[i]); }
    const unsigned short* HbB = Hb + ((size_t)ti * 3200 + b * 100) * 256;
#pragma unroll
    for (int j = 0; j < 14; ++j) {
      int s = srow0 + 8 * j;
      u32x2 o = {0u, 0u};
      if (s < 99) {
        int snode = s + (s >= r ? 1 : 0);
        u32x4 hb = *reinterpret_cast<const u32x4*>(HbB + snode * 256 + hc * 8);
        float t[8];
#pragma unroll
        for (int i = 0; i < 4; ++i) {
          t[2 * i] = tanh_fast(ha_f[2 * i] + bflo(hb[i]));
          t[2 * i + 1] = tanh_fast(ha_f[2 * i + 1] + bfhi(hb[i]));
        }
        o[0] = pk_fp8x4(t[0], t[1], t[2], t[3]);
        o[1] = pk_fp8x4(t[4], t[5], t[6], t[7]);
      }
      int byte = (s * 256 + hc * 8) ^ ((s & 7) << 4);
      *reinterpret_cast<u32x2*>(smem + byte) = o;
    }
    __syncthreads();   // m1 ready

    // fp8 GEMM in two SERIAL 32-col passes (runtime p -> one acc[7][2] live).
    const unsigned char* Bq = W2Q + (size_t)ti * 65536;
    const float* wsp = w_s + ti * 112;
#pragma unroll 1
    for (int p = 0; p < 2; ++p) {
      f32x4 acc[7][2];
#pragma unroll
      for (int m = 0; m < 7; ++m) { acc[m][0] = zz; acc[m][1] = zz; }
#pragma unroll
      for (int kk = 0; kk < 8; ++kk) {
        int ko = kk * 32 + lg * 8;
        long a[7];
#pragma unroll
        for (int m = 0; m < 7; ++m) {
          int row = m * 16 + li;
          int byte = (row * 256 + ko) ^ ((row & 7) << 4);
          a[m] = *reinterpret_cast<const long*>(smem + byte);
        }
#pragma unroll
        for (int n = 0; n < 2; ++n) {
          int col = wv * 64 + p * 32 + n * 16 + li;
          long bq = *reinterpret_cast<const long*>(Bq + col * 256 + ko);
#pragma unroll
          for (int m = 0; m < 7; ++m)
            acc[m][n] = __builtin_amdgcn_mfma_f32_16x16x32_fp8_fp8(a[m], bq, acc[m][n], 0, 0, 0);
        }
      }
      // epilogue for this pass (reg + broadcast-LDS; b2 loaded here, static idx)
      float s0 = 0.f, s1 = 0.f;
#pragma unroll
      for (int n = 0; n < 2; ++n) {
        float b2v = msg_b2[(ti + 1) * 256 + wv * 64 + p * 32 + n * 16 + li];
        float pa = 0.f;
#pragma unroll
        for (int m = 0; m < 7; ++m) {
          f32x4 wf = *reinterpret_cast<const f32x4*>(wsp + m * 16 + lg * 4);
#pragma unroll
          for (int q = 0; q < 4; ++q)
            pa += tanh_fast(acc[m][n][q] + b2v) * wf[q];
        }
        if (n == 0) s0 = pa; else s1 = pa;
      }
      if (p == 0) { agg0 += s0; agg1 += s1; }
      else        { agg2 += s0; agg3 += s1; }
    }
  }

  // reduce row-groups (C layout: col=lane&15, row=(lane>>4)*4+q)
  float aggacc[4] = {agg0, agg1, agg2, agg3};
#pragma unroll
  for (int n = 0; n < 4; ++n) {
    float v = aggacc[n];
    v += __shfl_xor(v, 16);
    v += __shfl_xor(v, 32);
    if (lane < 16) agg_s[wv * 64 + n * 16 + lane] = v;
  }
  __syncthreads();
  aggbf[(size_t)bid * 256 + tid] = f2bf(agg_s[tid]);
}

// ---- K3: RIH[y] = agg @ {Whr,Whi,Whh}[y] (f32 out) ----
__global__ __launch_bounds__(256) void k3_gemm(
    const unsigned short* __restrict__ aggbf, const unsigned short* __restrict__ WhT,
    float* __restrict__ RIH) {
  __shared__ alignas(16) unsigned char smem[32768];
  int tid = threadIdx.x, lane = tid & 63, wv = tid >> 6;
  int mt = blockIdx.x, y = blockIdx.y;
  stage_bf16_64(aggbf + (size_t)mt * 64 * 256, smem, tid);
  __syncthreads();
  f32x4 zz = {0.f, 0.f, 0.f, 0.f};
  f32x4 acc[4][4];
#pragma unroll
  for (int m = 0; m < 4; ++m)
#pragma unroll
    for (int n = 0; n < 4; ++n) acc[m][n] = zz;
  gemm_lds_tile<4>(smem, WhT + y * 65536, wv * 64, lane, acc);
  float* dst = RIH + (size_t)y * 819200 + (size_t)mt * 64 * 256;
  int li = lane & 15, lg = lane >> 4;
#pragma unroll
  for (int n = 0; n < 4; ++n) {
    int col = wv * 64 + n * 16 + li;
#pragma unroll
    for (int m = 0; m < 4; ++m)
#pragma unroll
      for (int q = 0; q < 4; ++q)
        dst[(m * 16 + lg * 4 + q) * 256 + col] = acc[m][n][q];
  }
}

// ---- K4: elementwise GRU combine -> hidden_new ----
__global__ __launch_bounds__(256) void k4_gru(
    const float* __restrict__ Xpre, const float* __restrict__ RIH,
    const float* __restrict__ hidden, float* __restrict__ out, unsigned short* __restrict__ hnewbf) {
  int idx = blockIdx.x * 256 + threadIdx.x;
  int row = idx >> 8, col = idx & 255;
  float xr = Xpre[row * 768 + col];
  float xi = Xpre[row * 768 + 256 + col];
  float xn = Xpre[row * 768 + 512 + col];
  float rr = sigmoid_fast(xr + RIH[idx]);
  float ig = sigmoid_fast(xi + RIH[819200 + idx]);
  float nn = tanh_fast(xn + rr * RIH[1638400 + idx]);
  float hn = (1.f - ig) * nn + ig * hidden[idx];
  out[12800 + idx] = hn;
  hnewbf[idx] = f2bf(hn);
}

// ---- K5/K6: dst = relu(A @ WT + bias) (bf16) ----
__global__ __launch_bounds__(256) void k_mlp(
    const unsigned short* __restrict__ A, const unsigned short* __restrict__ WT,
    const float* __restrict__ bias, unsigned short* __restrict__ dst) {
  __shared__ alignas(16) unsigned char smem[32768];
  int tid = threadIdx.x, lane = tid & 63, wv = tid >> 6;
  int mt = blockIdx.x;
  stage_bf16_64(A + (size_t)mt * 64 * 256, smem, tid);
  __syncthreads();
  f32x4 zz = {0.f, 0.f, 0.f, 0.f};
  f32x4 acc[4][4];
#pragma unroll
  for (int m = 0; m < 4; ++m)
#pragma unroll
    for (int n = 0; n < 4; ++n) acc[m][n] = zz;
  gemm_lds_tile<4>(smem, WT, wv * 64, lane, acc);
  unsigned short* d = dst + (size_t)mt * 64 * 256;
  int li = lane & 15, lg = lane >> 4;
#pragma unroll
  for (int n = 0; n < 4; ++n) {
    int col = wv * 64 + n * 16 + li;
    float bv = bias[col];
#pragma unroll
    for (int m = 0; m < 4; ++m)
#pragma unroll
      for (int q = 0; q < 4; ++q) {
        float v = fmaxf(acc[m][n][q] + bv, 0.f);
        d[(m * 16 + lg * 4 + q) * 256 + col] = f2bf(v);
      }
  }
}

// ---- K7: pred = inputs + pred2 @ Wo3 + bo3 ----
__global__ __launch_bounds__(64) void k7_out(
    const unsigned short* __restrict__ pred2, const float* __restrict__ Wo3,
    const float* __restrict__ bo3, const float* __restrict__ inputs, float* __restrict__ out) {
  int row = blockIdx.x, lane = threadIdx.x;
  u16x4 p = *reinterpret_cast<const u16x4*>(pred2 + (size_t)row * 256 + lane * 4);
  float s0 = 0.f, s1 = 0.f, s2 = 0.f, s3 = 0.f;
#pragma unroll
  for (int j = 0; j < 4; ++j) {
    float pv = bf2f(p[j]);
    const float* wr = Wo3 + (lane * 4 + j) * 4;
    s0 += pv * wr[0]; s1 += pv * wr[1]; s2 += pv * wr[2]; s3 += pv * wr[3];
  }
#pragma unroll
  for (int off = 32; off >= 1; off >>= 1) {
    s0 += __shfl_xor(s0, off); s1 += __shfl_xor(s1, off);
    s2 += __shfl_xor(s2, off); s3 += __shfl_xor(s3, off);
  }
  if (lane == 0) {
    out[row * 4 + 0] = inputs[row * 4 + 0] + s0 + bo3[0];
    out[row * 4 + 1] = inputs[row * 4 + 1] + s1 + bo3[1];
    out[row * 4 + 2] = inputs[row * 4 + 2] + s2 + bo3[2];
    out[row * 4 + 3] = inputs[row * 4 + 3] + s3 + bo3[3];
  }
}

extern "C" void kernel_launch(void* const* d_in, const int* in_sizes, int n_in,
                              void* d_out, int out_size, void* d_ws, size_t ws_size,
                              hipStream_t stream) {
  const float* inputs = (const float*)d_in[0];
  const float* hidden = (const float*)d_in[1];
  const float* edges  = (const float*)d_in[2];
  const float* msg_W1 = (const float*)d_in[3];
  const float* msg_b1 = (const float*)d_in[4];
  const float* msg_W2 = (const float*)d_in[5];
  const float* msg_b2 = (const float*)d_in[6];
  const float* Whr = (const float*)d_in[7];
  const float* Whi = (const float*)d_in[8];
  const float* Whh = (const float*)d_in[9];
  const float* Wir = (const float*)d_in[10];
  const float* bir = (const float*)d_in[11];
  const float* Wii = (const float*)d_in[12];
  const float* bii = (const float*)d_in[13];
  const float* Win = (const float*)d_in[14];
  const float* bin_ = (const float*)d_in[15];
  const float* Wo1 = (const float*)d_in[16];
  const float* bo1 = (const float*)d_in[17];
  const float* Wo2 = (const float*)d_in[18];
  const float* bo2 = (const float*)d_in[19];
  const float* Wo3 = (const float*)d_in[20];
  const float* bo3 = (const float*)d_in[21];
  float* out = (float*)d_out;

  char* ws = (char*)d_ws;
  size_t off = 0;
  auto take = [&](size_t bytes) -> char* {
    char* p = ws + off;
    off += (bytes + 511) & ~(size_t)511;
    return p;
  };
  unsigned short* W1aT = (unsigned short*)take(196608 * 2);
  unsigned short* W1bT = (unsigned short*)take(196608 * 2);
  unsigned short* W2Q  = (unsigned short*)take(196608);      // fp8 [3][256][256]
  unsigned short* WhT  = (unsigned short*)take(327680 * 2);  // WhrT|WhiT|WhhT|Wo1T|Wo2T
  unsigned short* Ha   = (unsigned short*)take(2457600 * 2); // [3][3200][256]
  unsigned short* Hb   = (unsigned short*)take(2457600 * 2);
  unsigned short* aggbf = (unsigned short*)take(819200 * 2);
  float* Xpre = (float*)take(2457600 * 4);                   // [3200][768]
  float* RIH  = (float*)take(2457600 * 4);                   // [3][3200][256]
  unsigned short* hnewbf = (unsigned short*)take(819200 * 2);
  unsigned short* pred1  = (unsigned short*)take(819200 * 2);
  unsigned short* pred2  = (unsigned short*)take(819200 * 2);

  k0_pack<<<2816, 256, 0, stream>>>(msg_W1, Whr, Whi, Whh, Wo1, Wo2, W1aT, W1bT, WhT);
  k0_quant<<<384, 256, 0, stream>>>(msg_W2, W2Q);
  k_xpre<<<9600, 256, 0, stream>>>(inputs, Wir, bir, Wii, bii, Win, bin_, Xpre);
  k1_nodepre<<<dim3(50, 6), 256, 0, stream>>>(hidden, msg_b1, W1aT, W1bT, Ha, Hb);
  k2_edges<<<3200, 256, 0, stream>>>(edges, msg_b2, Ha, Hb,
                                     (const unsigned char*)W2Q, aggbf);
  k3_gemm<<<dim3(50, 3), 256, 0, stream>>>(aggbf, WhT, RIH);
  k4_gru<<<3200, 256, 0, stream>>>(Xpre, RIH, hidden, out, hnewbf);
  k_mlp<<<50, 256, 0, stream>>>(hnewbf, WhT + 196608, bo1, pred1);
  k_mlp<<<50, 256, 0, stream>>>(pred1, WhT + 262144, bo2, pred2);
  k7_out<<<3200, 64, 0, stream>>>(pred2, Wo3, bo3, inputs, out);
}

// Round 12
// 354.166 us; speedup vs baseline: 1.3719x; 1.3719x over previous
//
#include <hip/hip_runtime.h>
#include <hip/hip_bf16.h>

// DNRI step: B=32, N=100, D=4, H=256, K=4 (skip type 0), E=9900.
// R11: decouple k2's phases. Conserved VALU-busy (~160us) + util pinned at
// ~42% across 7 structural variants + R4 (2 waves/SIMD, slower) => the limiter
// is barrier phase-coupling, not occupancy. Split:
//   k2a: streaming build -> global fp8 m1 slice (no barriers/LDS, high TLP)
//   k2b: stage slice -> swizzled LDS (pure copy), R9 GEMM + tanh epilogue
// Sequenced per-ti over one 91.7MB slice; partial aggs in f32 pagg[3],
// summed in k3 staging.

typedef __attribute__((ext_vector_type(4))) float f32x4;
typedef __attribute__((ext_vector_type(8))) short s16x8;
typedef __attribute__((ext_vector_type(4))) unsigned short u16x4;
typedef __attribute__((ext_vector_type(4))) unsigned int u32x4;
typedef __attribute__((ext_vector_type(2))) unsigned int u32x2;

#define DEV static __device__ __forceinline__

DEV unsigned short f2bf(float f) {
  unsigned int u = __builtin_bit_cast(unsigned int, f);
  u += 0x7fffu + ((u >> 16) & 1u);   // RNE
  return (unsigned short)(u >> 16);
}
DEV float bf2f(unsigned short h) {
  unsigned int u = ((unsigned int)h) << 16;
  return __builtin_bit_cast(float, u);
}
DEV float bflo(unsigned int u) { return __builtin_bit_cast(float, u << 16); }
DEV float bfhi(unsigned int u) { return __builtin_bit_cast(float, u & 0xffff0000u); }
DEV float exp2_fast(float x) { return __builtin_amdgcn_exp2f(x); }
DEV float tanh_fast(float x) {
  float e = exp2_fast(x * 2.885390082f);            // exp(2x)
  return 1.f - 2.f * __builtin_amdgcn_rcpf(e + 1.f);
}
DEV float sigmoid_fast(float x) {
  return __builtin_amdgcn_rcpf(1.f + exp2_fast(-1.442695041f * x));
}
DEV unsigned int pk_fp8x4(float a, float b, float c, float d) {
  int v = __builtin_amdgcn_cvt_pk_fp8_f32(a, b, 0, false);   // bytes 0,1
  v = __builtin_amdgcn_cvt_pk_fp8_f32(c, d, v, true);        // bytes 2,3
  return (unsigned int)v;
}

// ---- LDS staging: 64 rows x 256 bf16, XOR-swizzled ----
DEV void stage_bf16_64(const unsigned short* __restrict__ src, unsigned char* smem, int tid) {
#pragma unroll
  for (int j = 0; j < 8; ++j) {
    int c = tid + 256 * j;
    int s = c >> 5, hc = c & 31;
    s16x8 v = *reinterpret_cast<const s16x8*>(src + s * 256 + hc * 8);
    int byte = (s * 512 + hc * 16) ^ ((s & 7) << 4);
    *reinterpret_cast<s16x8*>(smem + byte) = v;
  }
}
DEV void stage_f32_64(const float* __restrict__ src, unsigned char* smem, int tid) {
#pragma unroll
  for (int j = 0; j < 8; ++j) {
    int c = tid + 256 * j;
    int s = c >> 5, hc = c & 31;
    const float* p = src + s * 256 + hc * 8;
    f32x4 v0 = *reinterpret_cast<const f32x4*>(p);
    f32x4 v1 = *reinterpret_cast<const f32x4*>(p + 4);
    s16x8 o;
#pragma unroll
    for (int i = 0; i < 4; ++i) { o[i] = (short)f2bf(v0[i]); o[4 + i] = (short)f2bf(v1[i]); }
    int byte = (s * 512 + hc * 16) ^ ((s & 7) << 4);
    *reinterpret_cast<s16x8*>(smem + byte) = o;
  }
}
// staging that sums three f32 partial buffers -> bf16 swizzled LDS
DEV void stage_sum3_f32(const float* __restrict__ sa, const float* __restrict__ sb,
                        const float* __restrict__ sc, unsigned char* smem, int tid) {
#pragma unroll
  for (int j = 0; j < 8; ++j) {
    int c = tid + 256 * j;
    int s = c >> 5, hc = c & 31;
    int o4 = s * 256 + hc * 8;
    f32x4 a0 = *reinterpret_cast<const f32x4*>(sa + o4);
    f32x4 a1 = *reinterpret_cast<const f32x4*>(sa + o4 + 4);
    f32x4 b0 = *reinterpret_cast<const f32x4*>(sb + o4);
    f32x4 b1 = *reinterpret_cast<const f32x4*>(sb + o4 + 4);
    f32x4 c0 = *reinterpret_cast<const f32x4*>(sc + o4);
    f32x4 c1 = *reinterpret_cast<const f32x4*>(sc + o4 + 4);
    s16x8 o;
#pragma unroll
    for (int i = 0; i < 4; ++i) {
      o[i] = (short)f2bf(a0[i] + b0[i] + c0[i]);
      o[4 + i] = (short)f2bf(a1[i] + b1[i] + c1[i]);
    }
    int byte = (s * 512 + hc * 16) ^ ((s & 7) << 4);
    *reinterpret_cast<s16x8*>(smem + byte) = o;
  }
}

// ---- bf16 MFMA tile helper (A in swizzled LDS, B^T [n][k] bf16 in global) ----
template<int MF>
DEV void gemm_lds_tile(const unsigned char* smemA, const unsigned short* __restrict__ B,
                       int nb, int lane, f32x4 acc[][4]) {
  int li = lane & 15, lg = lane >> 4;
#pragma unroll
  for (int kk = 0; kk < 8; ++kk) {
    int kb = kk * 32 + lg * 8;
    s16x8 a[MF];
#pragma unroll
    for (int m = 0; m < MF; ++m) {
      int row = m * 16 + li;
      int byte = (row * 512 + kb * 2) ^ ((row & 7) << 4);
      a[m] = *reinterpret_cast<const s16x8*>(smemA + byte);
    }
#pragma unroll
    for (int n = 0; n < 4; ++n) {
      int col = nb + n * 16 + li;
      s16x8 bf = *reinterpret_cast<const s16x8*>(B + col * 256 + kb);
#pragma unroll
      for (int m = 0; m < MF; ++m)
        acc[m][n] = __builtin_amdgcn_mfma_f32_16x16x32_bf16(a[m], bf, acc[m][n], 0, 0, 0);
    }
  }
}

// ---- K0: bf16 transposes (W1a/W1b/Wh-family) ----
__global__ __launch_bounds__(256) void k0_pack(
    const float* __restrict__ msg_W1,
    const float* __restrict__ Whr, const float* __restrict__ Whi, const float* __restrict__ Whh,
    const float* __restrict__ Wo1, const float* __restrict__ Wo2,
    unsigned short* __restrict__ W1aT, unsigned short* __restrict__ W1bT,
    unsigned short* __restrict__ WhT) {
  int g = blockIdx.x * 256 + threadIdx.x;
  if (g < 196608) {               // W1aT[ti][n][k] = msg_W1[ti+1][k][n]
    int ti = g >> 16, rem = g & 65535, n = rem >> 8, k = rem & 255;
    W1aT[g] = f2bf(msg_W1[((ti + 1) * 512 + k) * 256 + n]);
  } else if (g < 393216) {        // W1bT[ti][n][k] = msg_W1[ti+1][256+k][n]
    int h = g - 196608; int ti = h >> 16, rem = h & 65535, n = rem >> 8, k = rem & 255;
    W1bT[h] = f2bf(msg_W1[((ti + 1) * 512 + 256 + k) * 256 + n]);
  } else if (g < 720896) {        // WhT: {Whr,Whi,Whh,Wo1,Wo2}^T
    int h = g - 393216; int mi = h >> 16, rem = h & 65535, n = rem >> 8, k = rem & 255;
    const float* s = mi == 0 ? Whr : mi == 1 ? Whi : mi == 2 ? Whh : mi == 3 ? Wo1 : Wo2;
    WhT[h] = f2bf(s[k * 256 + n]);
  }
}

// ---- K0q: W2 -> fp8 e4m3, layout [ti][col][k] (1B/elem) ----
__global__ __launch_bounds__(256) void k0_quant(
    const float* __restrict__ msg_W2, unsigned short* __restrict__ W2Q) {
  int g = blockIdx.x * 256 + threadIdx.x;          // 98304 = 3*256*128
  int ti = g >> 15, rem = g & 32767, col = rem >> 7, k2 = rem & 127;
  int k = k2 * 2;
  const float* src = msg_W2 + (size_t)(ti + 1) * 65536;
  float a = src[k * 256 + col], b = src[(k + 1) * 256 + col];
  int v = __builtin_amdgcn_cvt_pk_fp8_f32(a, b, 0, false);
  W2Q[g] = (unsigned short)(v & 0xffff);
}

// ---- Xpre[row][3*256] = inputs @ [Wir|Wii|Win] + biases ----
__global__ __launch_bounds__(256) void k_xpre(
    const float* __restrict__ inputs, const float* __restrict__ Wir, const float* __restrict__ bir,
    const float* __restrict__ Wii, const float* __restrict__ bii,
    const float* __restrict__ Win, const float* __restrict__ bin_, float* __restrict__ Xpre) {
  int g = blockIdx.x * 256 + threadIdx.x;   // 3200*768 exact
  int row = g / 768, c = g % 768, which = c >> 8, col = c & 255;
  const float* W = which == 0 ? Wir : which == 1 ? Wii : Win;
  const float* bb = which == 0 ? bir : which == 1 ? bii : bin_;
  const float* inp = inputs + row * 4;
  float s = bb[col];
#pragma unroll
  for (int d = 0; d < 4; ++d) s += inp[d] * W[d * 256 + col];
  Xpre[g] = s;
}

// ---- K1: Ha[ti] = hidden@W1a+b1 (bf16), Hb[ti] = hidden@W1b ----
__global__ __launch_bounds__(256) void k1_nodepre(
    const float* __restrict__ hidden, const float* __restrict__ msg_b1,
    const unsigned short* __restrict__ W1aT, const unsigned short* __restrict__ W1bT,
    unsigned short* __restrict__ Ha, unsigned short* __restrict__ Hb) {
  __shared__ alignas(16) unsigned char smem[32768];
  int tid = threadIdx.x, lane = tid & 63, wv = tid >> 6;
  int mt = blockIdx.x, g = blockIdx.y;
  stage_f32_64(hidden + (size_t)mt * 64 * 256, smem, tid);
  __syncthreads();
  int ti = g < 3 ? g : g - 3;
  const unsigned short* Bp = (g < 3 ? W1aT : W1bT) + ti * 65536;
  f32x4 zz = {0.f, 0.f, 0.f, 0.f};
  f32x4 acc[4][4];
#pragma unroll
  for (int m = 0; m < 4; ++m)
#pragma unroll
    for (int n = 0; n < 4; ++n) acc[m][n] = zz;
  gemm_lds_tile<4>(smem, Bp, wv * 64, lane, acc);
  unsigned short* dst = (g < 3 ? Ha : Hb) + (size_t)ti * 819200 + (size_t)mt * 64 * 256;
  int li = lane & 15, lg = lane >> 4;
#pragma unroll
  for (int n = 0; n < 4; ++n) {
    int col = wv * 64 + n * 16 + li;
    float bias = g < 3 ? msg_b1[(ti + 1) * 256 + col] : 0.f;
#pragma unroll
    for (int m = 0; m < 4; ++m)
#pragma unroll
      for (int q = 0; q < 4; ++q) {
        int row = m * 16 + lg * 4 + q;
        dst[row * 256 + col] = f2bf(acc[m][n][q] + bias);
      }
  }
}

// ---- K2a: streaming build of one type-slice of m1 (fp8) to global ----
// grid 3200 (b,r); no LDS, no barriers. m1G[bid][112][256] bytes, rows 99..111 zero.
__global__ __launch_bounds__(256) void k2a_build(
    const unsigned short* __restrict__ Ha, const unsigned short* __restrict__ Hb,
    unsigned char* __restrict__ m1G, int ti) {
  int tid = threadIdx.x;
  int bid0 = blockIdx.x;
  int bid = (bid0 & 7) * 400 + (bid0 >> 3);   // XCD-contiguous (3200 = 8*400)
  int b = bid / 100, r = bid % 100;
  int hc = tid & 31, srow0 = tid >> 5;

  u32x4 hau = *reinterpret_cast<const u32x4*>(
      Ha + ((size_t)ti * 3200 + b * 100 + r) * 256 + hc * 8);
  float ha_f[8];
#pragma unroll
  for (int i = 0; i < 4; ++i) { ha_f[2 * i] = bflo(hau[i]); ha_f[2 * i + 1] = bfhi(hau[i]); }
  const unsigned short* HbB = Hb + ((size_t)ti * 3200 + b * 100) * 256;
  unsigned char* dst = m1G + (size_t)bid * 28672;
#pragma unroll
  for (int j = 0; j < 14; ++j) {
    int s = srow0 + 8 * j;
    u32x2 o = {0u, 0u};
    if (s < 99) {
      int snode = s + (s >= r ? 1 : 0);
      u32x4 hb = *reinterpret_cast<const u32x4*>(HbB + snode * 256 + hc * 8);
      float t[8];
#pragma unroll
      for (int i = 0; i < 4; ++i) {
        t[2 * i] = tanh_fast(ha_f[2 * i] + bflo(hb[i]));
        t[2 * i + 1] = tanh_fast(ha_f[2 * i + 1] + bfhi(hb[i]));
      }
      o[0] = pk_fp8x4(t[0], t[1], t[2], t[3]);
      o[1] = pk_fp8x4(t[4], t[5], t[6], t[7]);
    }
    *reinterpret_cast<u32x2*>(dst + s * 256 + hc * 8) = o;
  }
}

// ---- K2b: stage m1 slice -> swizzled LDS, fp8 GEMM, tanh epilogue -> pagg[ti] ----
// LDS: m1 fp8 [112][256B] swizzled @0 (28672) | w [112] f32 @28672 | agg [256] f32 @29120
__global__ __launch_bounds__(256) void k2b_gemm(
    const float* __restrict__ edges, const float* __restrict__ msg_b2,
    const unsigned char* __restrict__ m1G, const unsigned char* __restrict__ W2Q,
    float* __restrict__ pagg, int ti) {
  __shared__ alignas(16) unsigned char smem[30144];
  float* w_s = (float*)(smem + 28672);
  float* agg_s = (float*)(smem + 29120);
  int tid = threadIdx.x, lane = tid & 63, wv = tid >> 6;
  int li = lane & 15, lg = lane >> 4;
  int bid0 = blockIdx.x;
  int bid = (bid0 & 7) * 400 + (bid0 >> 3);
  int b = bid / 100, r = bid % 100;

  // edge weights for this type (analytic dense edge index)
  if (tid < 112) {
    float w0 = 0.f;
    if (tid < 99) {
      int snode = tid + (tid >= r ? 1 : 0);
      int e = snode * 99 + r - (r > snode ? 1 : 0);
      w0 = edges[(size_t)(b * 9900 + e) * 4 + (ti + 1)] * (1.f / 297.f);
    }
    w_s[tid] = w0;
  }
  // stage m1 slice -> swizzled LDS (pure copy, 7x16B per thread)
  const unsigned char* src = m1G + (size_t)bid * 28672;
#pragma unroll
  for (int jj = 0; jj < 7; ++jj) {
    int idx = tid + 256 * jj;
    int s = idx >> 4, c16 = (idx & 15) * 16;
    u32x4 v = *reinterpret_cast<const u32x4*>(src + s * 256 + c16);
    int byte = (s * 256 + c16) ^ ((s & 7) << 4);
    *reinterpret_cast<u32x4*>(smem + byte) = v;
  }
  __syncthreads();

  float b2r[4];
#pragma unroll
  for (int n = 0; n < 4; ++n)
    b2r[n] = msg_b2[(ti + 1) * 256 + wv * 64 + n * 16 + li];

  float aggacc[4] = {0.f, 0.f, 0.f, 0.f};
  f32x4 zz = {0.f, 0.f, 0.f, 0.f};
  const unsigned char* Bq = W2Q + (size_t)ti * 65536;
#pragma unroll
  for (int p = 0; p < 2; ++p) {
    f32x4 acc[7][2];
#pragma unroll
    for (int m = 0; m < 7; ++m) { acc[m][0] = zz; acc[m][1] = zz; }
#pragma unroll
    for (int kk = 0; kk < 8; ++kk) {
      int ko = kk * 32 + lg * 8;
      long a[7];
#pragma unroll
      for (int m = 0; m < 7; ++m) {
        int row = m * 16 + li;
        int byte = (row * 256 + ko) ^ ((row & 7) << 4);
        a[m] = *reinterpret_cast<const long*>(smem + byte);
      }
#pragma unroll
      for (int n = 0; n < 2; ++n) {
        int col = wv * 64 + p * 32 + n * 16 + li;
        long bq = *reinterpret_cast<const long*>(Bq + col * 256 + ko);
#pragma unroll
        for (int m = 0; m < 7; ++m)
          acc[m][n] = __builtin_amdgcn_mfma_f32_16x16x32_fp8_fp8(a[m], bq, acc[m][n], 0, 0, 0);
      }
    }
    // epilogue for this pass (reg + broadcast-LDS only)
#pragma unroll
    for (int n = 0; n < 2; ++n) {
      float b2v = b2r[p * 2 + n];
      float pa = 0.f;
#pragma unroll
      for (int m = 0; m < 7; ++m) {
        f32x4 wf = *reinterpret_cast<const f32x4*>(w_s + m * 16 + lg * 4);
#pragma unroll
        for (int q = 0; q < 4; ++q)
          pa += tanh_fast(acc[m][n][q] + b2v) * wf[q];
      }
      aggacc[p * 2 + n] += pa;
    }
  }

  // reduce row-groups (C layout: col=lane&15, row=(lane>>4)*4+q)
#pragma unroll
  for (int n = 0; n < 4; ++n) {
    float v = aggacc[n];
    v += __shfl_xor(v, 16);
    v += __shfl_xor(v, 32);
    if (lane < 16) agg_s[wv * 64 + n * 16 + lane] = v;
  }
  __syncthreads();
  pagg[(size_t)ti * 819200 + (size_t)bid * 256 + tid] = agg_s[tid];
}

// ---- K3: RIH[y] = (pagg0+pagg1+pagg2) @ {Whr,Whi,Whh}[y] (f32 out) ----
__global__ __launch_bounds__(256) void k3_gemm(
    const float* __restrict__ pagg, const unsigned short* __restrict__ WhT,
    float* __restrict__ RIH) {
  __shared__ alignas(16) unsigned char smem[32768];
  int tid = threadIdx.x, lane = tid & 63, wv = tid >> 6;
  int mt = blockIdx.x, y = blockIdx.y;
  size_t base = (size_t)mt * 64 * 256;
  stage_sum3_f32(pagg + base, pagg + 819200 + base, pagg + 1638400 + base, smem, tid);
  __syncthreads();
  f32x4 zz = {0.f, 0.f, 0.f, 0.f};
  f32x4 acc[4][4];
#pragma unroll
  for (int m = 0; m < 4; ++m)
#pragma unroll
    for (int n = 0; n < 4; ++n) acc[m][n] = zz;
  gemm_lds_tile<4>(smem, WhT + y * 65536, wv * 64, lane, acc);
  float* dst = RIH + (size_t)y * 819200 + base;
  int li = lane & 15, lg = lane >> 4;
#pragma unroll
  for (int n = 0; n < 4; ++n) {
    int col = wv * 64 + n * 16 + li;
#pragma unroll
    for (int m = 0; m < 4; ++m)
#pragma unroll
      for (int q = 0; q < 4; ++q)
        dst[(m * 16 + lg * 4 + q) * 256 + col] = acc[m][n][q];
  }
}

// ---- K4: elementwise GRU combine -> hidden_new ----
__global__ __launch_bounds__(256) void k4_gru(
    const float* __restrict__ Xpre, const float* __restrict__ RIH,
    const float* __restrict__ hidden, float* __restrict__ out, unsigned short* __restrict__ hnewbf) {
  int idx = blockIdx.x * 256 + threadIdx.x;
  int row = idx >> 8, col = idx & 255;
  float xr = Xpre[row * 768 + col];
  float xi = Xpre[row * 768 + 256 + col];
  float xn = Xpre[row * 768 + 512 + col];
  float rr = sigmoid_fast(xr + RIH[idx]);
  float ig = sigmoid_fast(xi + RIH[819200 + idx]);
  float nn = tanh_fast(xn + rr * RIH[1638400 + idx]);
  float hn = (1.f - ig) * nn + ig * hidden[idx];
  out[12800 + idx] = hn;
  hnewbf[idx] = f2bf(hn);
}

// ---- K5/K6: dst = relu(A @ WT + bias) (bf16) ----
__global__ __launch_bounds__(256) void k_mlp(
    const unsigned short* __restrict__ A, const unsigned short* __restrict__ WT,
    const float* __restrict__ bias, unsigned short* __restrict__ dst) {
  __shared__ alignas(16) unsigned char smem[32768];
  int tid = threadIdx.x, lane = tid & 63, wv = tid >> 6;
  int mt = blockIdx.x;
  stage_bf16_64(A + (size_t)mt * 64 * 256, smem, tid);
  __syncthreads();
  f32x4 zz = {0.f, 0.f, 0.f, 0.f};
  f32x4 acc[4][4];
#pragma unroll
  for (int m = 0; m < 4; ++m)
#pragma unroll
    for (int n = 0; n < 4; ++n) acc[m][n] = zz;
  gemm_lds_tile<4>(smem, WT, wv * 64, lane, acc);
  unsigned short* d = dst + (size_t)mt * 64 * 256;
  int li = lane & 15, lg = lane >> 4;
#pragma unroll
  for (int n = 0; n < 4; ++n) {
    int col = wv * 64 + n * 16 + li;
    float bv = bias[col];
#pragma unroll
    for (int m = 0; m < 4; ++m)
#pragma unroll
      for (int q = 0; q < 4; ++q) {
        float v = fmaxf(acc[m][n][q] + bv, 0.f);
        d[(m * 16 + lg * 4 + q) * 256 + col] = f2bf(v);
      }
  }
}

// ---- K7: pred = inputs + pred2 @ Wo3 + bo3 ----
__global__ __launch_bounds__(64) void k7_out(
    const unsigned short* __restrict__ pred2, const float* __restrict__ Wo3,
    const float* __restrict__ bo3, const float* __restrict__ inputs, float* __restrict__ out) {
  int row = blockIdx.x, lane = threadIdx.x;
  u16x4 p = *reinterpret_cast<const u16x4*>(pred2 + (size_t)row * 256 + lane * 4);
  float s0 = 0.f, s1 = 0.f, s2 = 0.f, s3 = 0.f;
#pragma unroll
  for (int j = 0; j < 4; ++j) {
    float pv = bf2f(p[j]);
    const float* wr = Wo3 + (lane * 4 + j) * 4;
    s0 += pv * wr[0]; s1 += pv * wr[1]; s2 += pv * wr[2]; s3 += pv * wr[3];
  }
#pragma unroll
  for (int off = 32; off >= 1; off >>= 1) {
    s0 += __shfl_xor(s0, off); s1 += __shfl_xor(s1, off);
    s2 += __shfl_xor(s2, off); s3 += __shfl_xor(s3, off);
  }
  if (lane == 0) {
    out[row * 4 + 0] = inputs[row * 4 + 0] + s0 + bo3[0];
    out[row * 4 + 1] = inputs[row * 4 + 1] + s1 + bo3[1];
    out[row * 4 + 2] = inputs[row * 4 + 2] + s2 + bo3[2];
    out[row * 4 + 3] = inputs[row * 4 + 3] + s3 + bo3[3];
  }
}

extern "C" void kernel_launch(void* const* d_in, const int* in_sizes, int n_in,
                              void* d_out, int out_size, void* d_ws, size_t ws_size,
                              hipStream_t stream) {
  const float* inputs = (const float*)d_in[0];
  const float* hidden = (const float*)d_in[1];
  const float* edges  = (const float*)d_in[2];
  const float* msg_W1 = (const float*)d_in[3];
  const float* msg_b1 = (const float*)d_in[4];
  const float* msg_W2 = (const float*)d_in[5];
  const float* msg_b2 = (const float*)d_in[6];
  const float* Whr = (const float*)d_in[7];
  const float* Whi = (const float*)d_in[8];
  const float* Whh = (const float*)d_in[9];
  const float* Wir = (const float*)d_in[10];
  const float* bir = (const float*)d_in[11];
  const float* Wii = (const float*)d_in[12];
  const float* bii = (const float*)d_in[13];
  const float* Win = (const float*)d_in[14];
  const float* bin_ = (const float*)d_in[15];
  const float* Wo1 = (const float*)d_in[16];
  const float* bo1 = (const float*)d_in[17];
  const float* Wo2 = (const float*)d_in[18];
  const float* bo2 = (const float*)d_in[19];
  const float* Wo3 = (const float*)d_in[20];
  const float* bo3 = (const float*)d_in[21];
  float* out = (float*)d_out;

  char* ws = (char*)d_ws;
  size_t off = 0;
  auto take = [&](size_t bytes) -> char* {
    char* p = ws + off;
    off += (bytes + 511) & ~(size_t)511;
    return p;
  };
  unsigned short* W1aT = (unsigned short*)take(196608 * 2);
  unsigned short* W1bT = (unsigned short*)take(196608 * 2);
  unsigned short* W2Q  = (unsigned short*)take(196608);      // fp8 [3][256][256]
  unsigned short* WhT  = (unsigned short*)take(327680 * 2);  // WhrT|WhiT|WhhT|Wo1T|Wo2T
  unsigned short* Ha   = (unsigned short*)take(2457600 * 2); // [3][3200][256]
  unsigned short* Hb   = (unsigned short*)take(2457600 * 2);
  float* pagg = (float*)take(3 * 819200 * 4);                // [3][3200][256] partial agg
  unsigned char* m1G = (unsigned char*)take((size_t)3200 * 28672); // one ti slice, 91.75MB
  float* Xpre = (float*)take(2457600 * 4);                   // [3200][768]
  float* RIH  = (float*)take(2457600 * 4);                   // [3][3200][256]
  unsigned short* hnewbf = (unsigned short*)take(819200 * 2);
  unsigned short* pred1  = (unsigned short*)take(819200 * 2);
  unsigned short* pred2  = (unsigned short*)take(819200 * 2);

  k0_pack<<<2816, 256, 0, stream>>>(msg_W1, Whr, Whi, Whh, Wo1, Wo2, W1aT, W1bT, WhT);
  k0_quant<<<384, 256, 0, stream>>>(msg_W2, W2Q);
  k_xpre<<<9600, 256, 0, stream>>>(inputs, Wir, bir, Wii, bii, Win, bin_, Xpre);
  k1_nodepre<<<dim3(50, 6), 256, 0, stream>>>(hidden, msg_b1, W1aT, W1bT, Ha, Hb);
  for (int ti = 0; ti < 3; ++ti) {
    k2a_build<<<3200, 256, 0, stream>>>(Ha, Hb, m1G, ti);
    k2b_gemm<<<3200, 256, 0, stream>>>(edges, msg_b2, m1G,
                                       (const unsigned char*)W2Q, pagg, ti);
  }
  k3_gemm<<<dim3(50, 3), 256, 0, stream>>>(pagg, WhT, RIH);
  k4_gru<<<3200, 256, 0, stream>>>(Xpre, RIH, hidden, out, hnewbf);
  k_mlp<<<50, 256, 0, stream>>>(hnewbf, WhT + 196608, bo1, pred1);
  k_mlp<<<50, 256, 0, stream>>>(pred1, WhT + 262144, bo2, pred2);
  k7_out<<<3200, 64, 0, stream>>>(pred2, Wo3, bo3, inputs, out);
}